// Round 1
// baseline (172.358 us; speedup 1.0000x reference)
//
#include <hip/hip_runtime.h>

// Median blur 3x3, replicate borders, NHWC fp32 [B, 512, 512, 3].
// Exact median-of-9 identity: partition the 3x3 window into its 3 rows,
// take (min, med, max) of each row, then
//   med9 = med3( max3(mins), med3(meds), min3(maxes) )
// This is the classic 19-CE median network collapsed onto gfx950's
// v_min3/v_med3/v_max3 instructions: 7 VALU ops per output.

#define IMG_H 512
#define IMG_W 512
#define IMG_C 3
#define ROW_F (IMG_W * IMG_C)   // 1536 floats per row
#define TILE_H 8                // rows per thread (vertical rolling window)

__device__ __forceinline__ float med3f(float a, float b, float c) {
    return __builtin_amdgcn_fmed3f(a, b, c);
}
__device__ __forceinline__ float min3f(float a, float b, float c) {
    return fminf(fminf(a, b), c);
}
__device__ __forceinline__ float max3f(float a, float b, float c) {
    return fmaxf(fmaxf(a, b), c);
}

__global__ __launch_bounds__(256) void median3x3_kernel(
        const float* __restrict__ in, float* __restrict__ out) {
    const int wc = blockIdx.x * blockDim.x + threadIdx.x;   // 0..1535 (w*3 + c)
    const int b  = blockIdx.z;
    const int h0 = blockIdx.y * TILE_H;

    const int w    = wc / 3;                   // channel-preserving column
    const int offL = (w == 0)         ? 0 : -3;
    const int offR = (w == IMG_W - 1) ? 0 :  3;

    const float* base  = in  + (size_t)b * IMG_H * ROW_F;
    float*       obase = out + (size_t)b * IMG_H * ROW_F;

    float mn0, md0, mx0, mn1, md1, mx1, mn2, md2, mx2;

    auto loadrow = [&](int r, float& mn, float& md, float& mx) {
        const float* p = base + (size_t)r * ROW_F + wc;
        float l = p[offL];
        float m = p[0];
        float rr = p[offR];
        mn = min3f(l, m, rr);
        md = med3f(l, m, rr);
        mx = max3f(l, m, rr);
    };

    // Prime the rolling window: rows h0-1 (clamped) and h0.
    loadrow((h0 == 0) ? 0 : h0 - 1, mn0, md0, mx0);
    loadrow(h0, mn1, md1, mx1);

    #pragma unroll
    for (int i = 0; i < TILE_H; ++i) {
        const int h  = h0 + i;
        const int hp = (h == IMG_H - 1) ? h : h + 1;   // replicate bottom edge
        loadrow(hp, mn2, md2, mx2);

        const float A  = max3f(mn0, mn1, mn2);
        const float Bm = med3f(md0, md1, md2);
        const float Cm = min3f(mx0, mx1, mx2);
        obase[(size_t)h * ROW_F + wc] = med3f(A, Bm, Cm);

        mn0 = mn1; md0 = md1; mx0 = mx1;
        mn1 = mn2; md1 = md2; mx1 = mx2;
    }
}

extern "C" void kernel_launch(void* const* d_in, const int* in_sizes, int n_in,
                              void* d_out, int out_size, void* d_ws, size_t ws_size,
                              hipStream_t stream) {
    const float* in = (const float*)d_in[0];
    float* out = (float*)d_out;

    const int B = in_sizes[0] / (IMG_H * ROW_F);   // 32

    dim3 grid(ROW_F / 256, IMG_H / TILE_H, B);     // (6, 64, 32)
    dim3 block(256, 1, 1);
    median3x3_kernel<<<grid, block, 0, stream>>>(in, out);
}